// Round 1
// baseline (414.139 us; speedup 1.0000x reference)
//
#include <hip/hip_runtime.h>
#include <cstdint>

#define S_LEN  2048
#define NH     16
#define DHEAD  64
#define DMODEL 1024

typedef __bf16 bf16x8 __attribute__((ext_vector_type(8)));
typedef float  f32x4  __attribute__((ext_vector_type(4)));

__device__ __forceinline__ unsigned short f2bf(float x) {
  union { float f; unsigned int u; } c; c.f = x;
  unsigned int u = c.u;
  return (unsigned short)((u + 0x7fffu + ((u >> 16) & 1u)) >> 16);
}

__device__ __forceinline__ void glds16(const void* g, void* l) {
  __builtin_amdgcn_global_load_lds(
      (const __attribute__((address_space(1))) void*)g,
      (__attribute__((address_space(3))) void*)l, 16, 0, 0);
}

__device__ __forceinline__ f32x4 mfma16(bf16x8 a, bf16x8 b, f32x4 c) {
  return __builtin_amdgcn_mfma_f32_16x16x32_bf16(a, b, c, 0, 0, 0);
}

// ---------------- fp32 -> bf16 convert ----------------
__global__ void cvt_kernel(const float* __restrict__ in,
                           unsigned short* __restrict__ out) {
  int i = (blockIdx.x * 256 + threadIdx.x) * 4;
  float4 v = *(const float4*)&in[i];
  ushort4 r;
  r.x = f2bf(v.x); r.y = f2bf(v.y); r.z = f2bf(v.z); r.w = f2bf(v.w);
  *(ushort4*)&out[i] = r;
}

// ---------------- GEMM: C[m,n] = sum_k A[m,k]*W[n,k]  (both K-contiguous) ----
// MODE 0: QKV. N=3072 (Q|K|V). bias per third; Q scaled by 0.125*log2e;
//         scatter to Qb/Kb [BH,S,64] and Vt [BH,64,S] as bf16.
// MODE 1: out-proj. N=1024, fp32 out += bias.
template<int MODE>
__global__ __launch_bounds__(256)
void gemm_bt(const unsigned short* __restrict__ A,
             const unsigned short* __restrict__ W,
             const float* __restrict__ bias0,
             const float* __restrict__ bias1,
             const float* __restrict__ bias2,
             unsigned short* __restrict__ Qb,
             unsigned short* __restrict__ Kb,
             unsigned short* __restrict__ Vt,
             float* __restrict__ Out,
             int K) {
  __shared__ __align__(16) unsigned short As[128 * 32];
  __shared__ __align__(16) unsigned short Bs[128 * 32];
  const int t    = threadIdx.x;
  const int lane = t & 63;
  const int w    = t >> 6;
  const int lr   = lane & 15, lq = lane >> 4;
  const int wm   = (w >> 1) * 64, wn = (w & 1) * 64;
  const int m0   = blockIdx.y * 128, n0 = blockIdx.x * 128;
  const int ra   = t >> 2, ca = (t & 3) * 8;

  f32x4 acc[4][4] = {};

  const int kt = K >> 5;
  for (int kk = 0; kk < kt; ++kk) {
    const int k0 = kk << 5;
    glds16(A + (m0 + ra) * K + k0 + ca,      &As[ra * 32 + ca]);
    glds16(A + (m0 + 64 + ra) * K + k0 + ca, &As[(64 + ra) * 32 + ca]);
    glds16(W + (n0 + ra) * K + k0 + ca,      &Bs[ra * 32 + ca]);
    glds16(W + (n0 + 64 + ra) * K + k0 + ca, &Bs[(64 + ra) * 32 + ca]);
    __syncthreads();
    bf16x8 af[4], bg[4];
#pragma unroll
    for (int i = 0; i < 4; ++i)
      af[i] = *(const bf16x8*)&As[(wm + i * 16 + lr) * 32 + lq * 8];
#pragma unroll
    for (int j = 0; j < 4; ++j)
      bg[j] = *(const bf16x8*)&Bs[(wn + j * 16 + lr) * 32 + lq * 8];
#pragma unroll
    for (int i = 0; i < 4; ++i)
#pragma unroll
      for (int j = 0; j < 4; ++j)
        acc[i][j] = mfma16(af[i], bg[j], acc[i][j]);
    __syncthreads();
  }

#pragma unroll
  for (int i = 0; i < 4; ++i) {
#pragma unroll
    for (int j = 0; j < 4; ++j) {
#pragma unroll
      for (int r = 0; r < 4; ++r) {
        const int m = m0 + wm + i * 16 + lq * 4 + r;
        const int n = n0 + wn + j * 16 + lr;
        float v = acc[i][j][r];
        if (MODE == 0) {
          const int tsel = n >> 10, d = n & 1023;
          const float* bp = (tsel == 0) ? bias0 : ((tsel == 1) ? bias1 : bias2);
          v += bp[d];
          const int bidx = m >> 11, s = m & (S_LEN - 1);
          const int h = d >> 6, dh = d & 63;
          const int bh = bidx * NH + h;
          if (tsel == 0) {
            v *= 0.125f * 1.44269504088896f;  // fold 1/sqrt(DH) * log2(e)
            Qb[(bh * S_LEN + s) * DHEAD + dh] = f2bf(v);
          } else if (tsel == 1) {
            Kb[(bh * S_LEN + s) * DHEAD + dh] = f2bf(v);
          } else {
            Vt[(bh * DHEAD + dh) * S_LEN + s] = f2bf(v);
          }
        } else {
          v += bias0[n];
          Out[m * DMODEL + n] = v;
        }
      }
    }
  }
}

// ---------------- flash attention (causal), one wave = 16 q rows ------------
__global__ __launch_bounds__(256)
void flash_kernel(const unsigned short* __restrict__ Qb,
                  const unsigned short* __restrict__ Kb,
                  const unsigned short* __restrict__ Vt,
                  unsigned short* __restrict__ Ocat) {
  __shared__ __align__(16) unsigned short pls[4][16 * 32];
  const int bh = blockIdx.y;
  const int w = threadIdx.x >> 6, lane = threadIdx.x & 63;
  const int lr = lane & 15, lq = lane >> 4;
  const int q0 = blockIdx.x * 64 + w * 16;
  const unsigned short* Qp = Qb + bh * (S_LEN * DHEAD);
  const unsigned short* Kp = Kb + bh * (S_LEN * DHEAD);
  const unsigned short* Vp = Vt + bh * (DHEAD * S_LEN);

  const bf16x8 qlo = *(const bf16x8*)&Qp[(q0 + lr) * DHEAD + lq * 8];
  const bf16x8 qhi = *(const bf16x8*)&Qp[(q0 + lr) * DHEAD + 32 + lq * 8];

  f32x4 o[4] = {};
  float mrow[4] = {-1e30f, -1e30f, -1e30f, -1e30f};
  float lrow[4] = {0.f, 0.f, 0.f, 0.f};

  const int skmax = q0 + 15;
  for (int sk0 = 0; sk0 <= skmax; sk0 += 32) {
    f32x4 s0 = {}, s1 = {};
    {
      const unsigned short* kb0 = &Kp[(sk0 + lr) * DHEAD + lq * 8];
      s0 = mfma16(qlo, *(const bf16x8*)kb0, s0);
      s0 = mfma16(qhi, *(const bf16x8*)(kb0 + 32), s0);
      const unsigned short* kb1 = kb0 + 16 * DHEAD;
      s1 = mfma16(qlo, *(const bf16x8*)kb1, s1);
      s1 = mfma16(qhi, *(const bf16x8*)(kb1 + 32), s1);
    }
#pragma unroll
    for (int r = 0; r < 4; ++r) {
      const int qrow = q0 + lq * 4 + r;
      const float a = (sk0 + lr <= qrow) ? s0[r] : -1e30f;
      const float b = (sk0 + 16 + lr <= qrow) ? s1[r] : -1e30f;
      float mx = fmaxf(a, b);
      mx = fmaxf(mx, __shfl_xor(mx, 1));
      mx = fmaxf(mx, __shfl_xor(mx, 2));
      mx = fmaxf(mx, __shfl_xor(mx, 4));
      mx = fmaxf(mx, __shfl_xor(mx, 8));
      const float nm = fmaxf(mrow[r], mx);
      const float alpha = exp2f(mrow[r] - nm);
      mrow[r] = nm;
      const float p0 = exp2f(a - nm);
      const float p1 = exp2f(b - nm);
      float ps = p0 + p1;
      ps += __shfl_xor(ps, 1);
      ps += __shfl_xor(ps, 2);
      ps += __shfl_xor(ps, 4);
      ps += __shfl_xor(ps, 8);
      lrow[r] = lrow[r] * alpha + ps;
#pragma unroll
      for (int tt = 0; tt < 4; ++tt) o[tt][r] *= alpha;
      pls[w][(lq * 4 + r) * 32 + lr]      = f2bf(p0);
      pls[w][(lq * 4 + r) * 32 + 16 + lr] = f2bf(p1);
    }
    // P: C/D layout -> A-operand layout via per-wave LDS (wave-synchronous)
    const bf16x8 pf = *(const bf16x8*)&pls[w][lr * 32 + lq * 8];
#pragma unroll
    for (int tt = 0; tt < 4; ++tt) {
      const bf16x8 vf = *(const bf16x8*)&Vp[(tt * 16 + lr) * S_LEN + sk0 + lq * 8];
      o[tt] = mfma16(pf, vf, o[tt]);
    }
  }

  const int bb = bh >> 4, h = bh & 15;
#pragma unroll
  for (int tt = 0; tt < 4; ++tt) {
#pragma unroll
    for (int r = 0; r < 4; ++r) {
      const int qrow = q0 + lq * 4 + r;
      const int dh = tt * 16 + lr;
      const float val = o[tt][r] / lrow[r];
      Ocat[(bb * S_LEN + qrow) * DMODEL + h * DHEAD + dh] = f2bf(val);
    }
  }
}

extern "C" void kernel_launch(void* const* d_in, const int* in_sizes, int n_in,
                              void* d_out, int out_size, void* d_ws, size_t ws_size,
                              hipStream_t stream) {
  const float* x  = (const float*)d_in[0];
  // d_in[1] = mask: deterministic causal tril — hardcoded in flash_kernel.
  const float* Wq = (const float*)d_in[2];
  const float* bq = (const float*)d_in[3];
  const float* Wk = (const float*)d_in[4];
  const float* bk = (const float*)d_in[5];
  const float* Wv = (const float*)d_in[6];
  const float* bv = (const float*)d_in[7];
  const float* Wo = (const float*)d_in[8];
  const float* bo = (const float*)d_in[9];
  float* out = (float*)d_out;

  char* ws = (char*)d_ws;
  unsigned short* xb   = (unsigned short*)(ws);                    // 8 MB [4096,1024]
  unsigned short* wqkv = (unsigned short*)(ws + (8ull  << 20));    // 6 MB [3072,1024]
  unsigned short* wo   = (unsigned short*)(ws + (14ull << 20));    // 2 MB [1024,1024]
  unsigned short* Qb   = (unsigned short*)(ws + (16ull << 20));    // 8 MB [32,2048,64]
  unsigned short* Kb   = (unsigned short*)(ws + (24ull << 20));    // 8 MB [32,2048,64]
  unsigned short* Vt   = (unsigned short*)(ws + (32ull << 20));    // 8 MB [32,64,2048]
  unsigned short* Ocat = (unsigned short*)(ws + (40ull << 20));    // 8 MB [4096,1024]

  cvt_kernel<<<4096, 256, 0, stream>>>(x, xb);
  cvt_kernel<<<1024, 256, 0, stream>>>(Wq, wqkv);
  cvt_kernel<<<1024, 256, 0, stream>>>(Wk, wqkv + (1 << 20));
  cvt_kernel<<<1024, 256, 0, stream>>>(Wv, wqkv + (2 << 20));
  cvt_kernel<<<1024, 256, 0, stream>>>(Wo, wo);

  gemm_bt<0><<<dim3(24, 32), 256, 0, stream>>>(xb, wqkv, bq, bk, bv,
                                               Qb, Kb, Vt, nullptr, 1024);
  flash_kernel<<<dim3(32, 32), 256, 0, stream>>>(Qb, Kb, Vt, Ocat);
  gemm_bt<1><<<dim3(8, 32), 256, 0, stream>>>(Ocat, wo, bo, nullptr, nullptr,
                                              nullptr, nullptr, nullptr, out, 1024);
}

// Round 2
// 325.534 us; speedup vs baseline: 1.2722x; 1.2722x over previous
//
#include <hip/hip_runtime.h>
#include <cstdint>

#define S_LEN  2048
#define NH     16
#define DHEAD  64
#define DMODEL 1024

typedef __bf16 bf16x8 __attribute__((ext_vector_type(8)));
typedef float  f32x4  __attribute__((ext_vector_type(4)));

__device__ __forceinline__ unsigned short f2bf(float x) {
  union { float f; unsigned int u; } c; c.f = x;
  unsigned int u = c.u;
  return (unsigned short)((u + 0x7fffu + ((u >> 16) & 1u)) >> 16);
}

__device__ __forceinline__ void glds16(const void* g, void* l) {
  __builtin_amdgcn_global_load_lds(
      (const __attribute__((address_space(1))) void*)g,
      (__attribute__((address_space(3))) void*)l, 16, 0, 0);
}

__device__ __forceinline__ f32x4 mfma16(bf16x8 a, bf16x8 b, f32x4 c) {
  return __builtin_amdgcn_mfma_f32_16x16x32_bf16(a, b, c, 0, 0, 0);
}

// ---------------- fp32 -> bf16 convert ----------------
__global__ void cvt_kernel(const float* __restrict__ in,
                           unsigned short* __restrict__ out) {
  int i = (blockIdx.x * 256 + threadIdx.x) * 4;
  float4 v = *(const float4*)&in[i];
  ushort4 r;
  r.x = f2bf(v.x); r.y = f2bf(v.y); r.z = f2bf(v.z); r.w = f2bf(v.w);
  *(ushort4*)&out[i] = r;
}

// ---------------- GEMM: C[m,n] = sum_k A[m,k]*W[n,k]  (both K-contiguous) ----
// MODE 0: QKV. N=3072 (Q|K|V). bias per third; Q scaled by 0.125*log2e;
//         scatter to Qb/Kb [BH,S,64] and Vt [BH,64,S] as bf16.
// MODE 1: out-proj. N=1024, fp32 out += bias.
template<int MODE>
__global__ __launch_bounds__(256)
void gemm_bt(const unsigned short* __restrict__ A,
             const unsigned short* __restrict__ W,
             const float* __restrict__ bias0,
             const float* __restrict__ bias1,
             const float* __restrict__ bias2,
             unsigned short* __restrict__ Qb,
             unsigned short* __restrict__ Kb,
             unsigned short* __restrict__ Vt,
             float* __restrict__ Out,
             int K) {
  __shared__ __align__(16) unsigned short As[128 * 32];
  __shared__ __align__(16) unsigned short Bs[128 * 32];
  const int t    = threadIdx.x;
  const int lane = t & 63;
  const int w    = t >> 6;
  const int lr   = lane & 15, lq = lane >> 4;
  const int wm   = (w >> 1) * 64, wn = (w & 1) * 64;
  const int m0   = blockIdx.y * 128, n0 = blockIdx.x * 128;
  const int ra   = t >> 2, ca = (t & 3) * 8;

  f32x4 acc[4][4] = {};

  const int kt = K >> 5;
  for (int kk = 0; kk < kt; ++kk) {
    const int k0 = kk << 5;
    glds16(A + (m0 + ra) * K + k0 + ca,      &As[ra * 32 + ca]);
    glds16(A + (m0 + 64 + ra) * K + k0 + ca, &As[(64 + ra) * 32 + ca]);
    glds16(W + (n0 + ra) * K + k0 + ca,      &Bs[ra * 32 + ca]);
    glds16(W + (n0 + 64 + ra) * K + k0 + ca, &Bs[(64 + ra) * 32 + ca]);
    __syncthreads();
    bf16x8 af[4], bg[4];
#pragma unroll
    for (int i = 0; i < 4; ++i)
      af[i] = *(const bf16x8*)&As[(wm + i * 16 + lr) * 32 + lq * 8];
#pragma unroll
    for (int j = 0; j < 4; ++j)
      bg[j] = *(const bf16x8*)&Bs[(wn + j * 16 + lr) * 32 + lq * 8];
#pragma unroll
    for (int i = 0; i < 4; ++i)
#pragma unroll
      for (int j = 0; j < 4; ++j)
        acc[i][j] = mfma16(af[i], bg[j], acc[i][j]);
    __syncthreads();
  }

#pragma unroll
  for (int i = 0; i < 4; ++i) {
#pragma unroll
    for (int j = 0; j < 4; ++j) {
#pragma unroll
      for (int r = 0; r < 4; ++r) {
        const int m = m0 + wm + i * 16 + lq * 4 + r;
        const int n = n0 + wn + j * 16 + lr;
        float v = acc[i][j][r];
        if (MODE == 0) {
          const int tsel = n >> 10, d = n & 1023;
          const float* bp = (tsel == 0) ? bias0 : ((tsel == 1) ? bias1 : bias2);
          v += bp[d];
          const int bidx = m >> 11, s = m & (S_LEN - 1);
          const int h = d >> 6, dh = d & 63;
          const int bh = bidx * NH + h;
          if (tsel == 0) {
            v *= 0.125f * 1.44269504088896f;  // fold 1/sqrt(DH) * log2(e)
            Qb[(bh * S_LEN + s) * DHEAD + dh] = f2bf(v);
          } else if (tsel == 1) {
            Kb[(bh * S_LEN + s) * DHEAD + dh] = f2bf(v);
          } else {
            Vt[(bh * DHEAD + dh) * S_LEN + s] = f2bf(v);
          }
        } else {
          v += bias0[n];
          Out[m * DMODEL + n] = v;
        }
      }
    }
  }
}

// ---------------- flash attention (causal), S^T formulation ------------------
// One wave = 16 q rows (q = lane&15), Sk tile = 64.
// S^T = mfma(K_frag, Q_frag): per-lane scores are one q-row -> row stats via
// 15 in-reg ops + 2 shuffles. O^T = mfma(V_frag, P_frag): alpha/l are
// lane-resident. Blocks pair strips b and 31-b for causal load balance.
__global__ __launch_bounds__(256)
void flash_kernel(const unsigned short* __restrict__ Qb,
                  const unsigned short* __restrict__ Kb,
                  const unsigned short* __restrict__ Vt,
                  unsigned short* __restrict__ Ocat) {
  __shared__ __align__(16) unsigned short pls[4][16 * 76];
  const int w = threadIdx.x >> 6, lane = threadIdx.x & 63;
  const int lr = lane & 15, lq = lane >> 4;
  const int bh = blockIdx.y;
  const unsigned short* Qp = Qb + bh * (S_LEN * DHEAD);
  const unsigned short* Kp = Kb + bh * (S_LEN * DHEAD);
  const unsigned short* Vp = Vt + bh * (DHEAD * S_LEN);
  const int bb = bh >> 4, h = bh & 15;
  unsigned short* pw = &pls[w][0];

  for (int strip = 0; strip < 2; ++strip) {
    const int sb = strip ? (31 - (int)blockIdx.x) : (int)blockIdx.x;
    const int q0 = sb * 64 + w * 16;
    const bf16x8 qlo = *(const bf16x8*)&Qp[(q0 + lr) * DHEAD + lq * 8];
    const bf16x8 qhi = *(const bf16x8*)&Qp[(q0 + lr) * DHEAD + 32 + lq * 8];

    f32x4 o[4] = {};
    float mrow = -1e30f, lrow = 0.f;
    const int nfull = q0 >> 6;  // tiles strictly below the diagonal

    for (int kt = 0; kt <= nfull; ++kt) {
      const int sk0 = kt << 6;
      f32x4 st[4] = {};
#pragma unroll
      for (int t = 0; t < 4; ++t) {
        const unsigned short* kb = &Kp[(sk0 + t * 16 + lr) * DHEAD + lq * 8];
        st[t] = mfma16(*(const bf16x8*)kb, qlo, st[t]);
        st[t] = mfma16(*(const bf16x8*)(kb + 32), qhi, st[t]);
      }
      float p[4][4];
      if (kt == nfull) {  // diagonal tile: apply causal mask
        const int q = q0 + lr;
#pragma unroll
        for (int t = 0; t < 4; ++t)
#pragma unroll
          for (int r = 0; r < 4; ++r) {
            const int k = sk0 + t * 16 + lq * 4 + r;
            p[t][r] = (k <= q) ? st[t][r] : -1e30f;
          }
      } else {
#pragma unroll
        for (int t = 0; t < 4; ++t)
#pragma unroll
          for (int r = 0; r < 4; ++r) p[t][r] = st[t][r];
      }
      float mx = p[0][0];
#pragma unroll
      for (int t = 0; t < 4; ++t)
#pragma unroll
        for (int r = 0; r < 4; ++r) mx = fmaxf(mx, p[t][r]);
      mx = fmaxf(mx, __shfl_xor(mx, 16));
      mx = fmaxf(mx, __shfl_xor(mx, 32));
      const float nm = fmaxf(mrow, mx);
      const float alpha = __builtin_amdgcn_exp2f(mrow - nm);
      mrow = nm;
      float ps = 0.f;
#pragma unroll
      for (int t = 0; t < 4; ++t)
#pragma unroll
        for (int r = 0; r < 4; ++r) {
          p[t][r] = __builtin_amdgcn_exp2f(p[t][r] - nm);
          ps += p[t][r];
        }
      ps += __shfl_xor(ps, 16);
      ps += __shfl_xor(ps, 32);
      lrow = lrow * alpha + ps;
#pragma unroll
      for (int tt = 0; tt < 4; ++tt) o[tt] *= alpha;

      // P^T (C layout) -> B-operand layout via per-wave LDS [q][k], stride 76
#pragma unroll
      for (int t = 0; t < 4; ++t) {
        ushort4 pk;
        pk.x = f2bf(p[t][0]); pk.y = f2bf(p[t][1]);
        pk.z = f2bf(p[t][2]); pk.w = f2bf(p[t][3]);
        *(ushort4*)&pw[lr * 76 + t * 16 + lq * 4] = pk;
      }
      const bf16x8 pf0 = *(const bf16x8*)&pw[lr * 76 + lq * 8];
      const bf16x8 pf1 = *(const bf16x8*)&pw[lr * 76 + 32 + lq * 8];
#pragma unroll
      for (int tt = 0; tt < 4; ++tt) {
        const unsigned short* vb = &Vp[(tt * 16 + lr) * S_LEN + sk0 + lq * 8];
        o[tt] = mfma16(*(const bf16x8*)vb, pf0, o[tt]);
        o[tt] = mfma16(*(const bf16x8*)(vb + 32), pf1, o[tt]);
      }
    }

    const float inv = 1.f / lrow;
#pragma unroll
    for (int tt = 0; tt < 4; ++tt) {
      ushort4 ov;
      ov.x = f2bf(o[tt][0] * inv); ov.y = f2bf(o[tt][1] * inv);
      ov.z = f2bf(o[tt][2] * inv); ov.w = f2bf(o[tt][3] * inv);
      *(ushort4*)&Ocat[(bb * S_LEN + q0 + lr) * DMODEL + h * DHEAD + tt * 16 + lq * 4] = ov;
    }
  }
}

extern "C" void kernel_launch(void* const* d_in, const int* in_sizes, int n_in,
                              void* d_out, int out_size, void* d_ws, size_t ws_size,
                              hipStream_t stream) {
  const float* x  = (const float*)d_in[0];
  // d_in[1] = mask: deterministic causal tril — hardcoded in flash_kernel.
  const float* Wq = (const float*)d_in[2];
  const float* bq = (const float*)d_in[3];
  const float* Wk = (const float*)d_in[4];
  const float* bk = (const float*)d_in[5];
  const float* Wv = (const float*)d_in[6];
  const float* bv = (const float*)d_in[7];
  const float* Wo = (const float*)d_in[8];
  const float* bo = (const float*)d_in[9];
  float* out = (float*)d_out;

  char* ws = (char*)d_ws;
  unsigned short* xb   = (unsigned short*)(ws);                    // 8 MB [4096,1024]
  unsigned short* wqkv = (unsigned short*)(ws + (8ull  << 20));    // 6 MB [3072,1024]
  unsigned short* wo   = (unsigned short*)(ws + (14ull << 20));    // 2 MB [1024,1024]
  unsigned short* Qb   = (unsigned short*)(ws + (16ull << 20));    // 8 MB [32,2048,64]
  unsigned short* Kb   = (unsigned short*)(ws + (24ull << 20));    // 8 MB [32,2048,64]
  unsigned short* Vt   = (unsigned short*)(ws + (32ull << 20));    // 8 MB [32,64,2048]
  unsigned short* Ocat = (unsigned short*)(ws + (40ull << 20));    // 8 MB [4096,1024]

  cvt_kernel<<<4096, 256, 0, stream>>>(x, xb);
  cvt_kernel<<<1024, 256, 0, stream>>>(Wq, wqkv);
  cvt_kernel<<<1024, 256, 0, stream>>>(Wk, wqkv + (1 << 20));
  cvt_kernel<<<1024, 256, 0, stream>>>(Wv, wqkv + (2 << 20));
  cvt_kernel<<<1024, 256, 0, stream>>>(Wo, wo);

  gemm_bt<0><<<dim3(24, 32), 256, 0, stream>>>(xb, wqkv, bq, bk, bv,
                                               Qb, Kb, Vt, nullptr, 1024);
  flash_kernel<<<dim3(16, 32), 256, 0, stream>>>(Qb, Kb, Vt, Ocat);
  gemm_bt<1><<<dim3(8, 32), 256, 0, stream>>>(Ocat, wo, bo, nullptr, nullptr,
                                              nullptr, nullptr, nullptr, out, 1024);
}

// Round 3
// 310.250 us; speedup vs baseline: 1.3349x; 1.0493x over previous
//
#include <hip/hip_runtime.h>
#include <cstdint>

#define S_LEN  2048
#define NH     16
#define DHEAD  64
#define DMODEL 1024

typedef __bf16 bf16x8 __attribute__((ext_vector_type(8)));
typedef float  f32x4  __attribute__((ext_vector_type(4)));

__device__ __forceinline__ unsigned short f2bf(float x) {
  union { float f; unsigned int u; } c; c.f = x;
  unsigned int u = c.u;
  return (unsigned short)((u + 0x7fffu + ((u >> 16) & 1u)) >> 16);
}

__device__ __forceinline__ void glds16(const void* g, void* l) {
  __builtin_amdgcn_global_load_lds(
      (const __attribute__((address_space(1))) void*)g,
      (__attribute__((address_space(3))) void*)l, 16, 0, 0);
}

__device__ __forceinline__ f32x4 mfma16(bf16x8 a, bf16x8 b, f32x4 c) {
  return __builtin_amdgcn_mfma_f32_16x16x32_bf16(a, b, c, 0, 0, 0);
}

// ---------------- fp32 -> bf16 convert ----------------
__global__ void cvt_kernel(const float* __restrict__ in,
                           unsigned short* __restrict__ out) {
  int i = (blockIdx.x * 256 + threadIdx.x) * 4;
  float4 v = *(const float4*)&in[i];
  ushort4 r;
  r.x = f2bf(v.x); r.y = f2bf(v.y); r.z = f2bf(v.z); r.w = f2bf(v.w);
  *(ushort4*)&out[i] = r;
}

// ---------------- GEMM: C[m,n] = sum_k A[m,k]*W[n,k]  (both K-contiguous) ----
template<int MODE>
__global__ __launch_bounds__(256)
void gemm_bt(const unsigned short* __restrict__ A,
             const unsigned short* __restrict__ W,
             const float* __restrict__ bias0,
             const float* __restrict__ bias1,
             const float* __restrict__ bias2,
             unsigned short* __restrict__ Qb,
             unsigned short* __restrict__ Kb,
             unsigned short* __restrict__ Vt,
             float* __restrict__ Out,
             int K) {
  __shared__ __align__(16) unsigned short As[128 * 32];
  __shared__ __align__(16) unsigned short Bs[128 * 32];
  const int t    = threadIdx.x;
  const int lane = t & 63;
  const int w    = t >> 6;
  const int lr   = lane & 15, lq = lane >> 4;
  const int wm   = (w >> 1) * 64, wn = (w & 1) * 64;
  const int m0   = blockIdx.y * 128, n0 = blockIdx.x * 128;
  const int ra   = t >> 2, ca = (t & 3) * 8;

  f32x4 acc[4][4] = {};

  const int kt = K >> 5;
  for (int kk = 0; kk < kt; ++kk) {
    const int k0 = kk << 5;
    glds16(A + (m0 + ra) * K + k0 + ca,      &As[ra * 32 + ca]);
    glds16(A + (m0 + 64 + ra) * K + k0 + ca, &As[(64 + ra) * 32 + ca]);
    glds16(W + (n0 + ra) * K + k0 + ca,      &Bs[ra * 32 + ca]);
    glds16(W + (n0 + 64 + ra) * K + k0 + ca, &Bs[(64 + ra) * 32 + ca]);
    __syncthreads();
    bf16x8 af[4], bg[4];
#pragma unroll
    for (int i = 0; i < 4; ++i)
      af[i] = *(const bf16x8*)&As[(wm + i * 16 + lr) * 32 + lq * 8];
#pragma unroll
    for (int j = 0; j < 4; ++j)
      bg[j] = *(const bf16x8*)&Bs[(wn + j * 16 + lr) * 32 + lq * 8];
#pragma unroll
    for (int i = 0; i < 4; ++i)
#pragma unroll
      for (int j = 0; j < 4; ++j)
        acc[i][j] = mfma16(af[i], bg[j], acc[i][j]);
    __syncthreads();
  }

#pragma unroll
  for (int i = 0; i < 4; ++i) {
#pragma unroll
    for (int j = 0; j < 4; ++j) {
#pragma unroll
      for (int r = 0; r < 4; ++r) {
        const int m = m0 + wm + i * 16 + lq * 4 + r;
        const int n = n0 + wn + j * 16 + lr;
        float v = acc[i][j][r];
        if (MODE == 0) {
          const int tsel = n >> 10, d = n & 1023;
          const float* bp = (tsel == 0) ? bias0 : ((tsel == 1) ? bias1 : bias2);
          v += bp[d];
          const int bidx = m >> 11, s = m & (S_LEN - 1);
          const int h = d >> 6, dh = d & 63;
          const int bh = bidx * NH + h;
          if (tsel == 0) {
            v *= 0.125f * 1.44269504088896f;  // fold 1/sqrt(DH) * log2(e)
            Qb[(bh * S_LEN + s) * DHEAD + dh] = f2bf(v);
          } else if (tsel == 1) {
            Kb[(bh * S_LEN + s) * DHEAD + dh] = f2bf(v);
          } else {
            Vt[(bh * DHEAD + dh) * S_LEN + s] = f2bf(v);
          }
        } else {
          v += bias0[n];
          Out[m * DMODEL + n] = v;
        }
      }
    }
  }
}

// ---------------- flash attention (causal), S^T + register prefetch ---------
// One wave = 16 q rows (q = lane&15), Sk tile = 64. S^T = mfma(K,Q) so row
// stats live per-lane (2 shuffles). Register double-buffered K/V prefetch:
// tile kt+1's 16 global b128 loads issue before tile kt's compute, so vmcnt
// waits are covered by ~1 tile of MFMA+softmax (AITER-style, never drain).
__global__ __launch_bounds__(256, 2)
void flash_kernel(const unsigned short* __restrict__ Qb,
                  const unsigned short* __restrict__ Kb,
                  const unsigned short* __restrict__ Vt,
                  unsigned short* __restrict__ Ocat) {
  __shared__ __align__(16) unsigned short pls[4][16 * 76];
  const int w = threadIdx.x >> 6, lane = threadIdx.x & 63;
  const int lr = lane & 15, lq = lane >> 4;
  const int bh = blockIdx.y;
  const unsigned short* Qp = Qb + bh * (S_LEN * DHEAD);
  const unsigned short* Kp = Kb + bh * (S_LEN * DHEAD);
  const unsigned short* Vp = Vt + bh * (DHEAD * S_LEN);
  const int bb = bh >> 4, h = bh & 15;
  unsigned short* pw = &pls[w][0];

  for (int strip = 0; strip < 2; ++strip) {
    const int sb = strip ? (31 - (int)blockIdx.x) : (int)blockIdx.x;
    const int q0 = sb * 64 + w * 16;
    const bf16x8 qlo = *(const bf16x8*)&Qp[(q0 + lr) * DHEAD + lq * 8];
    const bf16x8 qhi = *(const bf16x8*)&Qp[(q0 + lr) * DHEAD + 32 + lq * 8];

    f32x4 o[4] = {};
    float mrow = -1e30f, lrow = 0.f;
    const int nfull = q0 >> 6;  // index of the diagonal tile

    bf16x8 ka[8], va[8], kb8[8], vb8[8];

    auto loadKV = [&](bf16x8* kd, bf16x8* vd, int sk0) {
#pragma unroll
      for (int t = 0; t < 4; ++t) {
        const unsigned short* kp = &Kp[(sk0 + t * 16 + lr) * DHEAD + lq * 8];
        kd[2 * t]     = *(const bf16x8*)kp;
        kd[2 * t + 1] = *(const bf16x8*)(kp + 32);
        const unsigned short* vp = &Vp[(t * 16 + lr) * S_LEN + sk0 + lq * 8];
        vd[2 * t]     = *(const bf16x8*)vp;
        vd[2 * t + 1] = *(const bf16x8*)(vp + 32);
      }
    };

    auto compute = [&](const bf16x8* kf, const bf16x8* vf, int kt) {
      const int sk0 = kt << 6;
      f32x4 st[4] = {};
#pragma unroll
      for (int t = 0; t < 4; ++t) {
        st[t] = mfma16(kf[2 * t], qlo, st[t]);
        st[t] = mfma16(kf[2 * t + 1], qhi, st[t]);
      }
      float p[4][4];
      if (kt == nfull) {  // diagonal tile: causal mask
        const int q = q0 + lr;
#pragma unroll
        for (int t = 0; t < 4; ++t)
#pragma unroll
          for (int r = 0; r < 4; ++r) {
            const int k = sk0 + t * 16 + lq * 4 + r;
            p[t][r] = (k <= q) ? st[t][r] : -1e30f;
          }
      } else {
#pragma unroll
        for (int t = 0; t < 4; ++t)
#pragma unroll
          for (int r = 0; r < 4; ++r) p[t][r] = st[t][r];
      }
      float mx = p[0][0];
#pragma unroll
      for (int t = 0; t < 4; ++t)
#pragma unroll
        for (int r = 0; r < 4; ++r) mx = fmaxf(mx, p[t][r]);
      mx = fmaxf(mx, __shfl_xor(mx, 16));
      mx = fmaxf(mx, __shfl_xor(mx, 32));
      const float nm = fmaxf(mrow, mx);
      const float alpha = __builtin_amdgcn_exp2f(mrow - nm);
      mrow = nm;
      float ps = 0.f;
#pragma unroll
      for (int t = 0; t < 4; ++t)
#pragma unroll
        for (int r = 0; r < 4; ++r) {
          p[t][r] = __builtin_amdgcn_exp2f(p[t][r] - nm);
          ps += p[t][r];
        }
      ps += __shfl_xor(ps, 16);
      ps += __shfl_xor(ps, 32);
      lrow = lrow * alpha + ps;
#pragma unroll
      for (int tt = 0; tt < 4; ++tt) o[tt] *= alpha;

      // P^T (C layout) -> B-operand layout via per-wave LDS, stride 76
#pragma unroll
      for (int t = 0; t < 4; ++t) {
        ushort4 pk;
        pk.x = f2bf(p[t][0]); pk.y = f2bf(p[t][1]);
        pk.z = f2bf(p[t][2]); pk.w = f2bf(p[t][3]);
        *(ushort4*)&pw[lr * 76 + t * 16 + lq * 4] = pk;
      }
      const bf16x8 pf0 = *(const bf16x8*)&pw[lr * 76 + lq * 8];
      const bf16x8 pf1 = *(const bf16x8*)&pw[lr * 76 + 32 + lq * 8];
#pragma unroll
      for (int tt = 0; tt < 4; ++tt) {
        o[tt] = mfma16(vf[2 * tt], pf0, o[tt]);
        o[tt] = mfma16(vf[2 * tt + 1], pf1, o[tt]);
      }
    };

    loadKV(ka, va, 0);
    int kt = 0;
    for (;;) {
      {
        const int nk = (kt + 1 < nfull ? kt + 1 : nfull) << 6;
        loadKV(kb8, vb8, nk);  // prefetch (clamped; straight-line)
      }
      compute(ka, va, kt);
      if (++kt > nfull) break;
      {
        const int nk = (kt + 1 < nfull ? kt + 1 : nfull) << 6;
        loadKV(ka, va, nk);
      }
      compute(kb8, vb8, kt);
      if (++kt > nfull) break;
    }

    const float inv = 1.f / lrow;
#pragma unroll
    for (int tt = 0; tt < 4; ++tt) {
      ushort4 ov;
      ov.x = f2bf(o[tt][0] * inv); ov.y = f2bf(o[tt][1] * inv);
      ov.z = f2bf(o[tt][2] * inv); ov.w = f2bf(o[tt][3] * inv);
      *(ushort4*)&Ocat[(bb * S_LEN + q0 + lr) * DMODEL + h * DHEAD + tt * 16 + lq * 4] = ov;
    }
  }
}

extern "C" void kernel_launch(void* const* d_in, const int* in_sizes, int n_in,
                              void* d_out, int out_size, void* d_ws, size_t ws_size,
                              hipStream_t stream) {
  const float* x  = (const float*)d_in[0];
  // d_in[1] = mask: deterministic causal tril — hardcoded in flash_kernel.
  const float* Wq = (const float*)d_in[2];
  const float* bq = (const float*)d_in[3];
  const float* Wk = (const float*)d_in[4];
  const float* bk = (const float*)d_in[5];
  const float* Wv = (const float*)d_in[6];
  const float* bv = (const float*)d_in[7];
  const float* Wo = (const float*)d_in[8];
  const float* bo = (const float*)d_in[9];
  float* out = (float*)d_out;

  char* ws = (char*)d_ws;
  unsigned short* xb   = (unsigned short*)(ws);                    // 8 MB [4096,1024]
  unsigned short* wqkv = (unsigned short*)(ws + (8ull  << 20));    // 6 MB [3072,1024]
  unsigned short* wo   = (unsigned short*)(ws + (14ull << 20));    // 2 MB [1024,1024]
  unsigned short* Qb   = (unsigned short*)(ws + (16ull << 20));    // 8 MB [32,2048,64]
  unsigned short* Kb   = (unsigned short*)(ws + (24ull << 20));    // 8 MB [32,2048,64]
  unsigned short* Vt   = (unsigned short*)(ws + (32ull << 20));    // 8 MB [32,64,2048]
  unsigned short* Ocat = (unsigned short*)(ws + (40ull << 20));    // 8 MB [4096,1024]

  cvt_kernel<<<4096, 256, 0, stream>>>(x, xb);
  cvt_kernel<<<1024, 256, 0, stream>>>(Wq, wqkv);
  cvt_kernel<<<1024, 256, 0, stream>>>(Wk, wqkv + (1 << 20));
  cvt_kernel<<<1024, 256, 0, stream>>>(Wv, wqkv + (2 << 20));
  cvt_kernel<<<1024, 256, 0, stream>>>(Wo, wo);

  gemm_bt<0><<<dim3(24, 32), 256, 0, stream>>>(xb, wqkv, bq, bk, bv,
                                               Qb, Kb, Vt, nullptr, 1024);
  flash_kernel<<<dim3(16, 32), 256, 0, stream>>>(Qb, Kb, Vt, Ocat);
  gemm_bt<1><<<dim3(8, 32), 256, 0, stream>>>(Ocat, wo, bo, nullptr, nullptr,
                                              nullptr, nullptr, nullptr, out, 1024);
}

// Round 4
// 240.496 us; speedup vs baseline: 1.7220x; 1.2900x over previous
//
#include <hip/hip_runtime.h>
#include <cstdint>

#define S_LEN  2048
#define NH     16
#define DHEAD  64
#define DMODEL 1024

typedef __bf16 bf16x8 __attribute__((ext_vector_type(8)));
typedef float  f32x4  __attribute__((ext_vector_type(4)));

__device__ __forceinline__ unsigned short f2bf(float x) {
  union { float f; unsigned int u; } c; c.f = x;
  unsigned int u = c.u;
  return (unsigned short)((u + 0x7fffu + ((u >> 16) & 1u)) >> 16);
}

__device__ __forceinline__ void glds16(const void* g, void* l) {
  __builtin_amdgcn_global_load_lds(
      (const __attribute__((address_space(1))) void*)g,
      (__attribute__((address_space(3))) void*)l, 16, 0, 0);
}

__device__ __forceinline__ f32x4 mfma16(bf16x8 a, bf16x8 b, f32x4 c) {
  return __builtin_amdgcn_mfma_f32_16x16x32_bf16(a, b, c, 0, 0, 0);
}

// ---------------- fused fp32 -> bf16 convert (x + 4 weight mats) ------------
__global__ void cvt_all(const float* __restrict__ x,
                        const float* __restrict__ Wq,
                        const float* __restrict__ Wk,
                        const float* __restrict__ Wv,
                        const float* __restrict__ Wo,
                        unsigned short* __restrict__ xb,
                        unsigned short* __restrict__ wqkv,
                        unsigned short* __restrict__ wo) {
  const int b = blockIdx.x;
  const float* src;
  unsigned short* dst;
  int off;
  if (b < 4096)      { src = x;  dst = xb;                off = b; }
  else if (b < 5120) { src = Wq; dst = wqkv;              off = b - 4096; }
  else if (b < 6144) { src = Wk; dst = wqkv + (1 << 20);  off = b - 5120; }
  else if (b < 7168) { src = Wv; dst = wqkv + (2 << 20);  off = b - 6144; }
  else               { src = Wo; dst = wo;                off = b - 7168; }
  const int i = (off * 256 + threadIdx.x) * 4;
  float4 v = *(const float4*)&src[i];
  ushort4 r;
  r.x = f2bf(v.x); r.y = f2bf(v.y); r.z = f2bf(v.z); r.w = f2bf(v.w);
  *(ushort4*)&dst[i] = r;
}

// ---------------- GEMM: C[m,n] = sum_k A[m,k]*W[n,k]  (both K-contiguous) ----
template<int MODE>
__global__ __launch_bounds__(256)
void gemm_bt(const unsigned short* __restrict__ A,
             const unsigned short* __restrict__ W,
             const float* __restrict__ bias0,
             const float* __restrict__ bias1,
             const float* __restrict__ bias2,
             unsigned short* __restrict__ Qb,
             unsigned short* __restrict__ Kb,
             unsigned short* __restrict__ Vt,
             float* __restrict__ Out,
             int K) {
  __shared__ __align__(16) unsigned short As[128 * 32];
  __shared__ __align__(16) unsigned short Bs[128 * 32];
  const int t    = threadIdx.x;
  const int lane = t & 63;
  const int w    = t >> 6;
  const int lr   = lane & 15, lq = lane >> 4;
  const int wm   = (w >> 1) * 64, wn = (w & 1) * 64;
  const int m0   = blockIdx.y * 128, n0 = blockIdx.x * 128;
  const int ra   = t >> 2, ca = (t & 3) * 8;

  f32x4 acc[4][4] = {};

  const int kt = K >> 5;
  for (int kk = 0; kk < kt; ++kk) {
    const int k0 = kk << 5;
    glds16(A + (m0 + ra) * K + k0 + ca,      &As[ra * 32 + ca]);
    glds16(A + (m0 + 64 + ra) * K + k0 + ca, &As[(64 + ra) * 32 + ca]);
    glds16(W + (n0 + ra) * K + k0 + ca,      &Bs[ra * 32 + ca]);
    glds16(W + (n0 + 64 + ra) * K + k0 + ca, &Bs[(64 + ra) * 32 + ca]);
    __syncthreads();
    bf16x8 af[4], bg[4];
#pragma unroll
    for (int i = 0; i < 4; ++i)
      af[i] = *(const bf16x8*)&As[(wm + i * 16 + lr) * 32 + lq * 8];
#pragma unroll
    for (int j = 0; j < 4; ++j)
      bg[j] = *(const bf16x8*)&Bs[(wn + j * 16 + lr) * 32 + lq * 8];
#pragma unroll
    for (int i = 0; i < 4; ++i)
#pragma unroll
      for (int j = 0; j < 4; ++j)
        acc[i][j] = mfma16(af[i], bg[j], acc[i][j]);
    __syncthreads();
  }

#pragma unroll
  for (int i = 0; i < 4; ++i) {
#pragma unroll
    for (int j = 0; j < 4; ++j) {
#pragma unroll
      for (int r = 0; r < 4; ++r) {
        const int m = m0 + wm + i * 16 + lq * 4 + r;
        const int n = n0 + wn + j * 16 + lr;
        float v = acc[i][j][r];
        if (MODE == 0) {
          const int tsel = n >> 10, d = n & 1023;
          const float* bp = (tsel == 0) ? bias0 : ((tsel == 1) ? bias1 : bias2);
          v += bp[d];
          const int bidx = m >> 11, s = m & (S_LEN - 1);
          const int h = d >> 6, dh = d & 63;
          const int bh = bidx * NH + h;
          if (tsel == 0) {
            v *= 0.125f * 1.44269504088896f;  // fold 1/sqrt(DH) * log2(e)
            Qb[(bh * S_LEN + s) * DHEAD + dh] = f2bf(v);
          } else if (tsel == 1) {
            Kb[(bh * S_LEN + s) * DHEAD + dh] = f2bf(v);
          } else {
            Vt[(bh * DHEAD + dh) * S_LEN + s] = f2bf(v);
          }
        } else {
          v += bias0[n];
          Out[m * DMODEL + n] = v;
        }
      }
    }
  }
}

// ---------------- flash attention (causal), S^T + LDS-staged K/V ------------
// Block = 4 waves sharing one 64-row q-strip (wave w owns rows q0=sb*64+w*16),
// so all waves have identical tile trip counts. K/V 64x64 tiles staged in LDS
// (double-buffered) via global_load_lds width=16; the per-tile barrier gives a
// guaranteed 1-tile prefetch distance (m97 structure — compiler can't sink it).
// LDS tiles stored as two 64x32-short halves == gemm_bt's proven As geometry.
__global__ __launch_bounds__(256, 2)
void flash_kernel(const unsigned short* __restrict__ Qb,
                  const unsigned short* __restrict__ Kb,
                  const unsigned short* __restrict__ Vt,
                  unsigned short* __restrict__ Ocat) {
  __shared__ __align__(16) unsigned short Ks[2][2][64 * 32];
  __shared__ __align__(16) unsigned short Vs[2][2][64 * 32];
  __shared__ __align__(16) unsigned short pls[4][16 * 76];
  const int w = threadIdx.x >> 6, lane = threadIdx.x & 63;
  const int lr = lane & 15, lq = lane >> 4;
  const int bh = blockIdx.y;
  const char* Kc = (const char*)(Kb + bh * (S_LEN * DHEAD));
  const char* Vc = (const char*)(Vt + bh * (DHEAD * S_LEN));
  const unsigned short* Qp = Qb + bh * (S_LEN * DHEAD);
  const int bb = bh >> 4, h = bh & 15;
  unsigned short* pw = &pls[w][0];

  // staging split: wave w loads half hh = w&1, rowblocks rbb..rbb+1 (16 rows each)
  const int hh  = w & 1;
  const int rbb = (w >> 1) * 2;
  const int rlane = lane >> 2;          // row within 16-row block
  const int clane = (lane & 3) * 16;    // byte offset within 64 B half-row

  for (int strip = 0; strip < 2; ++strip) {
    const int sb = strip ? (31 - (int)blockIdx.x) : (int)blockIdx.x;
    const int q0 = sb * 64 + w * 16;
    const bf16x8 qlo = *(const bf16x8*)&Qp[(q0 + lr) * DHEAD + lq * 8];
    const bf16x8 qhi = *(const bf16x8*)&Qp[(q0 + lr) * DHEAD + 32 + lq * 8];

    f32x4 o[4] = {};
    float mrow = -1e30f, lrow = 0.f;
    const int nfull = sb;  // diagonal tile index (same for all 4 waves)

    auto stage = [&](int buf, int sk0) {
#pragma unroll
      for (int j = 0; j < 2; ++j) {
        const int rb = rbb + j;
        glds16(Kc + (sk0 + rb * 16 + rlane) * 128 + hh * 64 + clane,
               &Ks[buf][hh][rb * 16 * 32]);
        glds16(Vc + (rb * 16 + rlane) * 4096 + (sk0 + hh * 32) * 2 + clane,
               &Vs[buf][hh][rb * 16 * 32]);
      }
    };

    stage(0, 0);
    for (int kt = 0; kt <= nfull; ++kt) {
      const int buf = kt & 1;
      __syncthreads();                       // buf ready (vmcnt drain)
      if (kt < nfull) stage(1 - buf, (kt + 1) << 6);

      f32x4 st[4] = {};
      const unsigned short* Kl = Ks[buf][0];
      const unsigned short* Kh = Ks[buf][1];
#pragma unroll
      for (int t = 0; t < 4; ++t) {
        st[t] = mfma16(*(const bf16x8*)&Kl[(t * 16 + lr) * 32 + lq * 8], qlo, st[t]);
        st[t] = mfma16(*(const bf16x8*)&Kh[(t * 16 + lr) * 32 + lq * 8], qhi, st[t]);
      }
      float p[4][4];
      if (kt == nfull) {  // diagonal tile: causal mask
        const int q = q0 + lr, sk0 = kt << 6;
#pragma unroll
        for (int t = 0; t < 4; ++t)
#pragma unroll
          for (int r = 0; r < 4; ++r) {
            const int k = sk0 + t * 16 + lq * 4 + r;
            p[t][r] = (k <= q) ? st[t][r] : -1e30f;
          }
      } else {
#pragma unroll
        for (int t = 0; t < 4; ++t)
#pragma unroll
          for (int r = 0; r < 4; ++r) p[t][r] = st[t][r];
      }
      float mx = p[0][0];
#pragma unroll
      for (int t = 0; t < 4; ++t)
#pragma unroll
        for (int r = 0; r < 4; ++r) mx = fmaxf(mx, p[t][r]);
      mx = fmaxf(mx, __shfl_xor(mx, 16));
      mx = fmaxf(mx, __shfl_xor(mx, 32));
      const float nm = fmaxf(mrow, mx);
      const float alpha = __builtin_amdgcn_exp2f(mrow - nm);
      mrow = nm;
      float ps = 0.f;
#pragma unroll
      for (int t = 0; t < 4; ++t)
#pragma unroll
        for (int r = 0; r < 4; ++r) {
          p[t][r] = __builtin_amdgcn_exp2f(p[t][r] - nm);
          ps += p[t][r];
        }
      ps += __shfl_xor(ps, 16);
      ps += __shfl_xor(ps, 32);
      lrow = lrow * alpha + ps;
#pragma unroll
      for (int tt = 0; tt < 4; ++tt) o[tt] *= alpha;

      // P^T (C layout) -> B-operand layout via per-wave LDS, stride 76
#pragma unroll
      for (int t = 0; t < 4; ++t) {
        ushort4 pk;
        pk.x = f2bf(p[t][0]); pk.y = f2bf(p[t][1]);
        pk.z = f2bf(p[t][2]); pk.w = f2bf(p[t][3]);
        *(ushort4*)&pw[lr * 76 + t * 16 + lq * 4] = pk;
      }
      const bf16x8 pf0 = *(const bf16x8*)&pw[lr * 76 + lq * 8];
      const bf16x8 pf1 = *(const bf16x8*)&pw[lr * 76 + 32 + lq * 8];
      const unsigned short* Vl = Vs[buf][0];
      const unsigned short* Vh = Vs[buf][1];
#pragma unroll
      for (int tt = 0; tt < 4; ++tt) {
        o[tt] = mfma16(*(const bf16x8*)&Vl[(tt * 16 + lr) * 32 + lq * 8], pf0, o[tt]);
        o[tt] = mfma16(*(const bf16x8*)&Vh[(tt * 16 + lr) * 32 + lq * 8], pf1, o[tt]);
      }
    }

    const float inv = 1.f / lrow;
#pragma unroll
    for (int tt = 0; tt < 4; ++tt) {
      ushort4 ov;
      ov.x = f2bf(o[tt][0] * inv); ov.y = f2bf(o[tt][1] * inv);
      ov.z = f2bf(o[tt][2] * inv); ov.w = f2bf(o[tt][3] * inv);
      *(ushort4*)&Ocat[(bb * S_LEN + q0 + lr) * DMODEL + h * DHEAD + tt * 16 + lq * 4] = ov;
    }
    __syncthreads();  // all waves done with buffers before next strip restages
  }
}

extern "C" void kernel_launch(void* const* d_in, const int* in_sizes, int n_in,
                              void* d_out, int out_size, void* d_ws, size_t ws_size,
                              hipStream_t stream) {
  const float* x  = (const float*)d_in[0];
  // d_in[1] = mask: deterministic causal tril — hardcoded in flash_kernel.
  const float* Wq = (const float*)d_in[2];
  const float* bq = (const float*)d_in[3];
  const float* Wk = (const float*)d_in[4];
  const float* bk = (const float*)d_in[5];
  const float* Wv = (const float*)d_in[6];
  const float* bv = (const float*)d_in[7];
  const float* Wo = (const float*)d_in[8];
  const float* bo = (const float*)d_in[9];
  float* out = (float*)d_out;

  char* ws = (char*)d_ws;
  unsigned short* xb   = (unsigned short*)(ws);                    // 8 MB [4096,1024]
  unsigned short* wqkv = (unsigned short*)(ws + (8ull  << 20));    // 6 MB [3072,1024]
  unsigned short* wo   = (unsigned short*)(ws + (14ull << 20));    // 2 MB [1024,1024]
  unsigned short* Qb   = (unsigned short*)(ws + (16ull << 20));    // 8 MB [32,2048,64]
  unsigned short* Kb   = (unsigned short*)(ws + (24ull << 20));    // 8 MB [32,2048,64]
  unsigned short* Vt   = (unsigned short*)(ws + (32ull << 20));    // 8 MB [32,64,2048]
  unsigned short* Ocat = (unsigned short*)(ws + (40ull << 20));    // 8 MB [4096,1024]

  cvt_all<<<8192, 256, 0, stream>>>(x, Wq, Wk, Wv, Wo, xb, wqkv, wo);

  gemm_bt<0><<<dim3(24, 32), 256, 0, stream>>>(xb, wqkv, bq, bk, bv,
                                               Qb, Kb, Vt, nullptr, 1024);
  flash_kernel<<<dim3(16, 32), 256, 0, stream>>>(Qb, Kb, Vt, Ocat);
  gemm_bt<1><<<dim3(8, 32), 256, 0, stream>>>(Ocat, wo, bo, nullptr, nullptr,
                                              nullptr, nullptr, nullptr, out, 1024);
}